// Round 1
// baseline (181.169 us; speedup 1.0000x reference)
//
#include <hip/hip_runtime.h>
#include <hip/hip_bf16.h>

typedef __bf16 bf16x8 __attribute__((ext_vector_type(8)));
typedef float  f32x4  __attribute__((ext_vector_type(4)));

// ---------------------------------------------------------------------------
// async global->LDS, 16B per lane. Dest is wave-uniform base + lane*16.
__device__ __forceinline__ void gload16(const __bf16* g, __bf16* l) {
  __builtin_amdgcn_global_load_lds(
      (const __attribute__((address_space(1))) void*)g,
      (__attribute__((address_space(3))) void*)l, 16, 0, 0);
}

// Stage a 128x64 bf16 tile (rows x k) into 16KB of LDS.
// LDS is written linearly (chunk c at byte c*16); the *source* is permuted so
// that LDS content is XOR-swizzled: logical slot s of row r lives at phys slot
// s ^ (r&7). Reads must apply the same XOR (rule 21: both-sides-or-neither).
__device__ __forceinline__ void stage_tile(const __bf16* __restrict__ g, int ld,
                                           __bf16* l, int wid, int lane) {
#pragma unroll
  for (int p = 0; p < 4; ++p) {
    int c    = p * 256 + wid * 64 + lane;   // 16B chunk index, 0..1023
    int row  = c >> 3;                      // 8 chunks (128B) per row
    int slog = (c & 7) ^ (row & 7);         // inverse-swizzled source slot
    gload16(g + (long)row * ld + slog * 8,
            l + (p * 256 + wid * 64) * 8);  // wave-uniform dest
  }
}

// swizzled LDS byte offset for logical (row, 16B-slot s)
__device__ __forceinline__ int lds_off(int r, int s) {
  return r * 128 + ((s * 16) ^ ((r & 7) << 4));
}

// ---------------------------------------------------------------------------
// C[M][N] = A[M][K] * Bt[N][K]^T   (both operands row-major, K contiguous)
// 128x128 tile, BK=64, 256 threads = 4 waves in 2x2, each wave 64x64 output.
// OUTBF16: store __bf16 else float. BIASMODE: 0 none, 1 bias[col], 2 bias[row].
// DOSCALE: multiply by scale before bias.
template <int OUTBF16, int BIASMODE, int DOSCALE>
__global__ __launch_bounds__(256, 2) void gemm_bt(
    const __bf16* __restrict__ A, const __bf16* __restrict__ Bt,
    const float* __restrict__ bias, void* __restrict__ Cv,
    int lda, int ldb, int ldc, int K,
    long sA, long sB, long sC, float scale) {
  __shared__ __bf16 lds[2][2][128 * 64];  // [buf][A/B][tile] = 64 KiB

  const int tid = threadIdx.x, wid = tid >> 6, lane = tid & 63;
  const int wr = wid >> 1, wc = wid & 1;
  const long brow = (long)blockIdx.y * 128;
  const long bcol = (long)blockIdx.x * 128;

  A  += (long)blockIdx.z * sA;
  Bt += (long)blockIdx.z * sB;

  const __bf16* ga = A + brow * lda;
  const __bf16* gb = Bt + bcol * ldb;
  const int nk = K >> 6;

  f32x4 zero = {0.f, 0.f, 0.f, 0.f};
  f32x4 acc[4][4];
#pragma unroll
  for (int m = 0; m < 4; ++m)
#pragma unroll
    for (int n = 0; n < 4; ++n) acc[m][n] = zero;

  // prologue: stage tile 0 into buf 0
  stage_tile(ga, lda, &lds[0][0][0], wid, lane);
  stage_tile(gb, ldb, &lds[0][1][0], wid, lane);
  __syncthreads();

  for (int kt = 0; kt < nk; ++kt) {
    const int cur = kt & 1;
    // issue next-tile prefetch BEFORE compute (loads fly under the MFMAs)
    if (kt + 1 < nk) {
      stage_tile(ga + (kt + 1) * 64, lda, &lds[cur ^ 1][0][0], wid, lane);
      stage_tile(gb + (kt + 1) * 64, ldb, &lds[cur ^ 1][1][0], wid, lane);
    }
    const char* Ab = (const char*)&lds[cur][0][0];
    const char* Bb = (const char*)&lds[cur][1][0];
#pragma unroll
    for (int ks = 0; ks < 2; ++ks) {
      bf16x8 af[4], bfr[4];
      const int s = ks * 4 + (lane >> 4);
#pragma unroll
      for (int m = 0; m < 4; ++m) {
        int r = wr * 64 + m * 16 + (lane & 15);
        af[m] = *(const bf16x8*)(Ab + lds_off(r, s));
      }
#pragma unroll
      for (int n = 0; n < 4; ++n) {
        int r = wc * 64 + n * 16 + (lane & 15);
        bfr[n] = *(const bf16x8*)(Bb + lds_off(r, s));
      }
#pragma unroll
      for (int m = 0; m < 4; ++m)
#pragma unroll
        for (int n = 0; n < 4; ++n)
          acc[m][n] = __builtin_amdgcn_mfma_f32_16x16x32_bf16(
              af[m], bfr[n], acc[m][n], 0, 0, 0);
    }
    __syncthreads();  // drains prefetch (overlapped with MFMA) + protects bufs
  }

  // epilogue: C/D layout col = lane&15, row = (lane>>4)*4 + reg
  const long cbase = (long)blockIdx.z * sC;
#pragma unroll
  for (int m = 0; m < 4; ++m) {
    const int row = (int)brow + wr * 64 + m * 16 + ((lane >> 4) << 2);
#pragma unroll
    for (int n = 0; n < 4; ++n) {
      const int col = (int)bcol + wc * 64 + n * 16 + (lane & 15);
#pragma unroll
      for (int r = 0; r < 4; ++r) {
        float v = acc[m][n][r];
        if (DOSCALE) v *= scale;
        if (BIASMODE == 1) v += bias[col];
        if (BIASMODE == 2) v += bias[row + r];
        if (OUTBF16)
          ((__bf16*)Cv)[cbase + (long)(row + r) * ldc + col] = (__bf16)v;
        else
          ((float*)Cv)[cbase + (long)(row + r) * ldc + col] = v;
      }
    }
  }
}

// ---------------------------------------------------------------------------
// x fp32 -> bf16, 8 elements/thread, exact coverage
__global__ __launch_bounds__(256) void convert_x(const float* __restrict__ x,
                                                 __bf16* __restrict__ o) {
  const long i = ((long)blockIdx.x * 256 + threadIdx.x) * 8;
  float4 a = *(const float4*)(x + i);
  float4 b = *(const float4*)(x + i + 4);
  bf16x8 v;
  v[0] = (__bf16)a.x; v[1] = (__bf16)a.y; v[2] = (__bf16)a.z; v[3] = (__bf16)a.w;
  v[4] = (__bf16)b.x; v[5] = (__bf16)b.y; v[6] = (__bf16)b.z; v[7] = (__bf16)b.w;
  *(bf16x8*)(o + i) = v;
}

// W[1024][1024] fp32 -> Wt[1024][1024] bf16 transposed; 64x64 tiles.
__global__ __launch_bounds__(256) void transpose_w(
    const float* __restrict__ W0, const float* __restrict__ W1,
    const float* __restrict__ W2, __bf16* __restrict__ T0,
    __bf16* __restrict__ T1, __bf16* __restrict__ T2) {
  const float* W = blockIdx.z == 0 ? W0 : (blockIdx.z == 1 ? W1 : W2);
  __bf16* T      = blockIdx.z == 0 ? T0 : (blockIdx.z == 1 ? T1 : T2);
  __shared__ float t[64][65];
  const int e0 = blockIdx.x * 64, d0 = blockIdx.y * 64;
  const int tr = threadIdx.x >> 2, tc = (threadIdx.x & 3) * 16;
  const float* src = W + (long)(d0 + tr) * 1024 + e0 + tc;
#pragma unroll
  for (int i = 0; i < 4; ++i) {
    float4 v = *(const float4*)(src + i * 4);
    t[tr][tc + i * 4 + 0] = v.x;
    t[tr][tc + i * 4 + 1] = v.y;
    t[tr][tc + i * 4 + 2] = v.z;
    t[tr][tc + i * 4 + 3] = v.w;
  }
  __syncthreads();
  // write Wt[e][d] = t[d_local][e_local], 16 bf16 (32B) per thread, coalesced
  __bf16* dst = T + (long)(e0 + tr) * 1024 + d0 + tc;
  bf16x8 v0, v1;
#pragma unroll
  for (int i = 0; i < 8; ++i) v0[i] = (__bf16)t[tc + i][tr];
#pragma unroll
  for (int i = 0; i < 8; ++i) v1[i] = (__bf16)t[tc + 8 + i][tr];
  *(bf16x8*)dst = v0;
  *(bf16x8*)(dst + 8) = v1;
}

// in-place row softmax over 2048 bf16, one block per row, fp32 reduction
__global__ __launch_bounds__(256) void softmax_rows(__bf16* __restrict__ P) {
  __bf16* p = P + (long)blockIdx.x * 2048;
  const int t = threadIdx.x, wid = t >> 6, lane = t & 63;
  bf16x8 v = *(bf16x8*)(p + t * 8);
  float f[8];
  float mx = -1e30f;
#pragma unroll
  for (int i = 0; i < 8; ++i) { f[i] = (float)v[i]; mx = fmaxf(mx, f[i]); }
#pragma unroll
  for (int o = 32; o > 0; o >>= 1) mx = fmaxf(mx, __shfl_xor(mx, o));
  __shared__ float redm[4], reds[4];
  if (lane == 0) redm[wid] = mx;
  __syncthreads();
  mx = fmaxf(fmaxf(redm[0], redm[1]), fmaxf(redm[2], redm[3]));
  float s = 0.f;
#pragma unroll
  for (int i = 0; i < 8; ++i) { f[i] = __expf(f[i] - mx); s += f[i]; }
#pragma unroll
  for (int o = 32; o > 0; o >>= 1) s += __shfl_xor(s, o);
  if (lane == 0) reds[wid] = s;
  __syncthreads();
  s = reds[0] + reds[1] + reds[2] + reds[3];
  const float inv = 1.0f / s;
#pragma unroll
  for (int i = 0; i < 8; ++i) v[i] = (__bf16)(f[i] * inv);
  *(bf16x8*)(p + t * 8) = v;
}

// ---------------------------------------------------------------------------
extern "C" void kernel_launch(void* const* d_in, const int* in_sizes, int n_in,
                              void* d_out, int out_size, void* d_ws,
                              size_t ws_size, hipStream_t stream) {
  const float* x  = (const float*)d_in[0];
  const float* Wq = (const float*)d_in[1];
  const float* bq = (const float*)d_in[2];
  const float* Wk = (const float*)d_in[3];
  const float* bk = (const float*)d_in[4];
  const float* Wv = (const float*)d_in[5];
  const float* bv = (const float*)d_in[6];
  float* out = (float*)d_out;

  char* ws = (char*)d_ws;
  __bf16* xb  = (__bf16*)(ws);                    // 16 MB: x bf16 [8192][1024]
  __bf16* wqt = (__bf16*)(ws + (16l << 20));      //  2 MB: Wq^T
  __bf16* wkt = (__bf16*)(ws + (18l << 20));      //  2 MB: Wk^T
  __bf16* wvt = (__bf16*)(ws + (20l << 20));      //  2 MB: Wv^T
  __bf16* q   = (__bf16*)(ws + (22l << 20));      // 16 MB: Q [8192][1024]
  __bf16* kk  = (__bf16*)(ws + (38l << 20));      // 16 MB: K [8192][1024]
  __bf16* vt  = (__bf16*)(ws + (54l << 20));      // 16 MB: V^T [1024][8192]
  __bf16* S   = (__bf16*)(ws + (70l << 20));      // 32 MB: S/P [4][2048][2048]

  convert_x<<<4096, 256, 0, stream>>>(x, xb);
  transpose_w<<<dim3(16, 16, 3), 256, 0, stream>>>(Wq, Wk, Wv, wqt, wkt, wvt);

  // Q = xb * Wq^T^T + bq  (M=8192 tokens, N=1024, K=1024), bf16 out
  gemm_bt<1, 1, 0><<<dim3(8, 64, 1), 256, 0, stream>>>(
      xb, wqt, bq, q, 1024, 1024, 1024, 1024, 0, 0, 0, 1.f);
  gemm_bt<1, 1, 0><<<dim3(8, 64, 1), 256, 0, stream>>>(
      xb, wkt, bk, kk, 1024, 1024, 1024, 1024, 0, 0, 0, 1.f);
  // V^T directly: Vt[e][token] = Wvt[e][:] . xb[token][:] + bv[e]
  // (M=1024 features, N=8192 tokens), bf16 out, bias per ROW
  gemm_bt<1, 2, 0><<<dim3(64, 8, 1), 256, 0, stream>>>(
      wvt, xb, bv, vt, 1024, 1024, 8192, 1024, 0, 0, 0, 1.f);

  // S = Q K^T * (1/32)  per batch (M=N=2048, K=1024), bf16 out
  gemm_bt<1, 0, 1><<<dim3(16, 16, 4), 256, 0, stream>>>(
      q, kk, nullptr, S, 1024, 1024, 2048, 1024,
      2048l * 1024, 2048l * 1024, 2048l * 2048, 0.03125f);

  softmax_rows<<<8192, 256, 0, stream>>>(S);

  // O = P V  per batch (M=2048, N=1024, K=2048), fp32 out to d_out.
  // B^T operand is vt with ld 8192, per-batch column offset 2048.
  gemm_bt<0, 0, 0><<<dim3(8, 16, 4), 256, 0, stream>>>(
      S, vt, nullptr, out, 2048, 8192, 1024, 2048,
      2048l * 2048, 2048, 2048l * 1024, 1.f);
}